// Round 4
// baseline (100.599 us; speedup 1.0000x reference)
//
#include <hip/hip_runtime.h>
#include <hip/hip_bf16.h>

// ARAP local step, round 4.
// Round-3 post-mortem: 1 thread/vertex = 1.5 waves/SIMD -> divergent-gather
// LATENCY bound (cutting instr count 3x bought only 5%). Fix: edge-parallel
// gather with 16 lanes/vertex (25k waves, ~24 waves/SIMD), shfl_xor reduction
// of the 3x3 covariance within 16-lane groups, S staged SoA in d_ws; then a
// light vertex-parallel eigensolve kernel (Horn quaternion via 16 symmetric
// squarings of the shifted PD 4x4 — verified rounds 2-3, absmax 3.9e-3).

__global__ __launch_bounds__(256)
void prepack_kernel(const float* __restrict__ xyz1,
                    const float* __restrict__ xyz2,
                    float4* __restrict__ pk,   // [B*N][2] float4 (32B/vertex)
                    int total)
{
    int t = blockIdx.x * blockDim.x + threadIdx.x;
    if (t >= total) return;
    float4 a, c;
    a.x = xyz1[t * 3 + 0]; a.y = xyz1[t * 3 + 1]; a.z = xyz1[t * 3 + 2]; a.w = 0.f;
    c.x = xyz2[t * 3 + 0]; c.y = xyz2[t * 3 + 1]; c.z = xyz2[t * 3 + 2]; c.w = 0.f;
    pk[2 * (size_t)t + 0] = a;
    pk[2 * (size_t)t + 1] = c;
}

// 16 lanes per (b,i) vertex; lane k handles neighbors k, k+16, ...
__global__ __launch_bounds__(256)
void gather_kernel(const float4* __restrict__ pk,
                   const int*   __restrict__ nbr,
                   const int*   __restrict__ num,
                   const int*   __restrict__ acc,
                   const float* __restrict__ wgt,
                   float*       __restrict__ Sout,  // SoA: [9][B*N]
                   int B, int N)
{
    int tid = blockIdx.x * blockDim.x + threadIdx.x;
    int v = tid >> 4;          // vertex work-item (b*N + i)
    int k = tid & 15;          // lane within vertex group
    int total = B * N;
    if (v >= total) return;
    int b = v / N;
    int i = v - b * N;

    const float4* base = pk + 2 * (size_t)b * N;
    float4 P1 = base[2 * i + 0];     // 16 lanes same addr -> broadcast-friendly
    float4 P2 = base[2 * i + 1];

    int a0  = acc[i];
    int cnt = num[i];

    float Sxx = 0.f, Sxy = 0.f, Sxz = 0.f;
    float Syx = 0.f, Syy = 0.f, Syz = 0.f;
    float Szx = 0.f, Szy = 0.f, Szz = 0.f;

    for (int kk = k; kk < cnt; kk += 16) {
        int   e  = a0 + kk;
        int   j  = nbr[e];            // contiguous within the 16-lane run
        float we = wgt[e];
        float4 A = base[2 * j + 0];   // divergent dwordx4, same 64B line pair
        float4 C = base[2 * j + 1];
        float d1x = P1.x - A.x, d1y = P1.y - A.y, d1z = P1.z - A.z;
        float d2x = P2.x - C.x, d2y = P2.y - C.y, d2z = P2.z - C.z;
        float w1x = we * d1x, w1y = we * d1y, w1z = we * d1z;
        Sxx += w1x * d2x;  Sxy += w1x * d2y;  Sxz += w1x * d2z;
        Syx += w1y * d2x;  Syy += w1y * d2y;  Syz += w1y * d2z;
        Szx += w1z * d2x;  Szy += w1z * d2y;  Szz += w1z * d2z;
    }

    // Reduce across the 16-lane group (xor masks 1,2,4,8 stay in-group).
#pragma unroll
    for (int m = 8; m >= 1; m >>= 1) {
        Sxx += __shfl_xor(Sxx, m);  Sxy += __shfl_xor(Sxy, m);  Sxz += __shfl_xor(Sxz, m);
        Syx += __shfl_xor(Syx, m);  Syy += __shfl_xor(Syy, m);  Syz += __shfl_xor(Syz, m);
        Szx += __shfl_xor(Szx, m);  Szy += __shfl_xor(Szy, m);  Szz += __shfl_xor(Szz, m);
    }

    if (k == 0) {
        size_t st = (size_t)total;
        Sout[0 * st + v] = Sxx;  Sout[1 * st + v] = Sxy;  Sout[2 * st + v] = Sxz;
        Sout[3 * st + v] = Syx;  Sout[4 * st + v] = Syy;  Sout[5 * st + v] = Syz;
        Sout[6 * st + v] = Szx;  Sout[7 * st + v] = Szy;  Sout[8 * st + v] = Szz;
    }
}

__global__ __launch_bounds__(256)
void solve_kernel(const float* __restrict__ Sin,   // SoA: [9][B*N]
                  float*       __restrict__ out,
                  int total)
{
    int t = blockIdx.x * blockDim.x + threadIdx.x;
    if (t >= total) return;
    size_t st = (size_t)total;
    float Sxx = Sin[0 * st + t], Sxy = Sin[1 * st + t], Sxz = Sin[2 * st + t];
    float Syx = Sin[3 * st + t], Syy = Sin[4 * st + t], Syz = Sin[5 * st + t];
    float Szx = Sin[6 * st + t], Szy = Sin[7 * st + t], Szz = Sin[8 * st + t];

    // Horn's 4x4 symmetric matrix (q = [w,x,y,z]); maps d1 -> d2.
    float n00 =  Sxx + Syy + Szz;
    float n01 =  Syz - Szy;
    float n02 =  Szx - Sxz;
    float n03 =  Sxy - Syx;
    float n11 =  Sxx - Syy - Szz;
    float n12 =  Sxy + Syx;
    float n13 =  Szx + Sxz;
    float n22 = -Sxx + Syy - Szz;
    float n23 =  Syz + Szy;
    float n33 = -Sxx - Syy + Szz;

    float fro2 = Sxx*Sxx + Sxy*Sxy + Sxz*Sxz
               + Syx*Syx + Syy*Syy + Syz*Syz
               + Szx*Szx + Szy*Szy + Szz*Szz;
    float s = 2.0f * sqrtf(fro2) + 1e-30f;

    float m00 = n00 + s, m01 = n01, m02 = n02, m03 = n03;
    float m11 = n11 + s, m12 = n12, m13 = n13;
    float m22 = n22 + s, m23 = n23;
    float m33 = n33 + s;

    {
        float inv = 1.0f / (m00 + m11 + m22 + m33);
        m00 *= inv; m01 *= inv; m02 *= inv; m03 *= inv;
        m11 *= inv; m12 *= inv; m13 *= inv;
        m22 *= inv; m23 *= inv; m33 *= inv;
    }

    // 16 symmetric squarings with trace renorm: M^(2^16) -> c*v*v^T.
#pragma unroll
    for (int it = 0; it < 16; ++it) {
        float p00 = m00*m00 + m01*m01 + m02*m02 + m03*m03;
        float p01 = m00*m01 + m01*m11 + m02*m12 + m03*m13;
        float p02 = m00*m02 + m01*m12 + m02*m22 + m03*m23;
        float p03 = m00*m03 + m01*m13 + m02*m23 + m03*m33;
        float p11 = m01*m01 + m11*m11 + m12*m12 + m13*m13;
        float p12 = m01*m02 + m11*m12 + m12*m22 + m13*m23;
        float p13 = m01*m03 + m11*m13 + m12*m23 + m13*m33;
        float p22 = m02*m02 + m12*m12 + m22*m22 + m23*m23;
        float p23 = m02*m03 + m12*m13 + m22*m23 + m23*m33;
        float p33 = m03*m03 + m13*m13 + m23*m23 + m33*m33;
        float inv = 1.0f / (p00 + p11 + p22 + p33);
        m00 = p00 * inv; m01 = p01 * inv; m02 = p02 * inv; m03 = p03 * inv;
        m11 = p11 * inv; m12 = p12 * inv; m13 = p13 * inv;
        m22 = p22 * inv; m23 = p23 * inv;
        m33 = p33 * inv;
    }

    // Column with the largest diagonal entry == top eigenvector.
    float qw = m00, qx = m01, qy = m02, qz = m03, best = m00;
    {
        bool g = m11 > best;
        qw = g ? m01 : qw; qx = g ? m11 : qx; qy = g ? m12 : qy; qz = g ? m13 : qz;
        best = g ? m11 : best;
        g = m22 > best;
        qw = g ? m02 : qw; qx = g ? m12 : qx; qy = g ? m22 : qy; qz = g ? m23 : qz;
        best = g ? m22 : best;
        g = m33 > best;
        qw = g ? m03 : qw; qx = g ? m13 : qx; qy = g ? m23 : qy; qz = g ? m33 : qz;
    }
    {
        float inv = rsqrtf(qw*qw + qx*qx + qy*qy + qz*qz);
        qw *= inv; qx *= inv; qy *= inv; qz *= inv;
    }

    float xx = qx*qx, yy = qy*qy, zz = qz*qz;
    float xy = qx*qy, xz = qx*qz, yz = qy*qz;
    float wx = qw*qx, wy = qw*qy, wz = qw*qz;

    float* o = out + (size_t)t * 9;
    o[0] = 1.f - 2.f*(yy + zz);
    o[1] = 2.f*(xy - wz);
    o[2] = 2.f*(xz + wy);
    o[3] = 2.f*(xy + wz);
    o[4] = 1.f - 2.f*(xx + zz);
    o[5] = 2.f*(yz - wx);
    o[6] = 2.f*(xz - wy);
    o[7] = 2.f*(yz + wx);
    o[8] = 1.f - 2.f*(xx + yy);
}

extern "C" void kernel_launch(void* const* d_in, const int* in_sizes, int n_in,
                              void* d_out, int out_size, void* d_ws, size_t ws_size,
                              hipStream_t stream) {
    const float* xyz1 = (const float*)d_in[0];
    const float* xyz2 = (const float*)d_in[1];
    const int*   nbr  = (const int*)  d_in[2];
    const int*   num  = (const int*)  d_in[3];
    const int*   acc  = (const int*)  d_in[4];
    const float* wgt  = (const float*)d_in[5];
    float* out = (float*)d_out;

    int N = in_sizes[3];               // numNeighbors has N entries
    int B = in_sizes[0] / (N * 3);     // xyz1 is [B,N,3]
    int total = B * N;

    // Workspace layout: pk [total*2 float4] = 32B/vertex, then S SoA [9][total].
    float4* pk = (float4*)d_ws;
    float*  Sb = (float*)((char*)d_ws + (size_t)total * 32);

    int block = 256;
    prepack_kernel<<<(total + block - 1) / block, block, 0, stream>>>(
        xyz1, xyz2, pk, total);
    int gthreads = total * 16;
    gather_kernel<<<(gthreads + block - 1) / block, block, 0, stream>>>(
        pk, nbr, num, acc, wgt, Sb, B, N);
    solve_kernel<<<(total + block - 1) / block, block, 0, stream>>>(
        Sb, out, total);
}